// Round 11
// baseline (173.078 us; speedup 1.0000x reference)
//
#include <hip/hip_runtime.h>
#include <hip/hip_bf16.h>
#include <math.h>

#define B 8
#define N 1024
#define F 256
#define H 8
#define D 64
#define HD 512  // H*D
#define NBLK 512

typedef __attribute__((ext_vector_type(8))) short bf16x8;
typedef __attribute__((ext_vector_type(16))) float f32x16;

__device__ __forceinline__ ushort f2bf(float x) {
    __hip_bfloat16 b = __float2bfloat16(x);
    return *reinterpret_cast<ushort*>(&b);
}

// async global->LDS, 16B per lane; lds dest = wave-uniform base + lane*16
__device__ __forceinline__ void gl_lds16(const void* g, void* l) {
    __builtin_amdgcn_global_load_lds(
        (__attribute__((address_space(1))) void*)const_cast<void*>(g),
        (__attribute__((address_space(3))) void*)l, 16, 0, 0);
}

#define SWZ(r, byte) ((byte) ^ (((r) & 7) << 4))

// ---------------------------------------------------------------------------
// Software grid barrier. Grid must be <= co-resident capacity (512 blocks:
// 2/CU by 64KB LDS). Device-scope acq/rel per G16; state in __device__
// globals: cnt self-restores to 0 each launch, gen only grows (compared for
// change only) -> deterministic across graph replays, immune to ws poison.
// ---------------------------------------------------------------------------
__device__ unsigned g_cnt = 0;
__device__ unsigned g_gen = 0;

__device__ __forceinline__ void gbar() {
    __syncthreads();
    if (threadIdx.x == 0) {
        unsigned g = __hip_atomic_load(&g_gen, __ATOMIC_RELAXED, __HIP_MEMORY_SCOPE_AGENT);
        unsigned old = __hip_atomic_fetch_add(&g_cnt, 1u, __ATOMIC_ACQ_REL, __HIP_MEMORY_SCOPE_AGENT);
        if (old == (unsigned)(NBLK - 1)) {
            __hip_atomic_store(&g_cnt, 0u, __ATOMIC_RELAXED, __HIP_MEMORY_SCOPE_AGENT);
            __hip_atomic_fetch_add(&g_gen, 1u, __ATOMIC_ACQ_REL, __HIP_MEMORY_SCOPE_AGENT);
        } else {
            while (__hip_atomic_load(&g_gen, __ATOMIC_ACQUIRE, __HIP_MEMORY_SCOPE_AGENT) == g)
                __builtin_amdgcn_s_sleep(8);
        }
    }
    __syncthreads();
}

// ---------------------------------------------------------------------------
// Mega-kernel: 512 blocks x 256 threads.
// A: row norms -> hn bf16 + nrm (16 rows/block) ; Wt transpose (256/block).
// B: 800 work items, 2 grid-stride passes. x=wq&7 (XCD/batch), q=wq>>3:
//    q<64 proj (64Mx128N, out+src/tgt epilogue); q>=64 adj (128x128 ti<=tj
//    + mirrored words). 2-phase dbuf prefetch, 1 barrier/K-step.
// C: fixup attention (16 rows/block); singleton rows skip.
// ---------------------------------------------------------------------------
__global__ __launch_bounds__(256, 2) void k_mega(const float* __restrict__ h,
                                                 const float* __restrict__ W,
                                                 const float* __restrict__ a,
                                                 ushort* __restrict__ hn,
                                                 ushort* __restrict__ Wt,
                                                 float* __restrict__ nrm,
                                                 float* __restrict__ out,
                                                 float* __restrict__ src,
                                                 float* __restrict__ tgt,
                                                 unsigned* __restrict__ adj) {
    __shared__ __align__(16) ushort S[2][16384];  // per buf: A 16KB | B 16KB
    __shared__ float norms[64];
    const int t = threadIdx.x;
    const int lane = t & 63;
    const int w = t >> 6;
    const int wr = w >> 1, wc = w & 1;

    // ---------------- Phase A: prep ----------------
    {
        #pragma unroll
        for (int k = 0; k < 4; ++k) {
            int row = blockIdx.x * 16 + w * 4 + k;   // 0..8191
            float4 v = *reinterpret_cast<const float4*>(h + (size_t)row * F + lane * 4);
            float s = v.x * v.x + v.y * v.y + v.z * v.z + v.w * v.w;
            #pragma unroll
            for (int off = 32; off; off >>= 1) s += __shfl_xor(s, off, 64);
            float sn = fmaxf(s, 1e-12f);
            float inv = rsqrtf(sn);
            ushort4 on;
            on.x = f2bf(v.x * inv); on.y = f2bf(v.y * inv);
            on.z = f2bf(v.z * inv); on.w = f2bf(v.w * inv);
            *reinterpret_cast<ushort4*>(hn + (size_t)row * F + lane * 4) = on;
            if (lane == 0) nrm[row] = sn * inv;  // = sqrt(sn)
        }
        int idx = blockIdx.x * 256 + t;  // 0..131071, coalesced over n
        Wt[(size_t)(idx & 511) * F + (idx >> 9)] = f2bf(W[idx]);
    }
    gbar();

    // ---------------- Phase B: fused MFMA ----------------
    const int lr = lane >> 3;                  // row within 8-row chunk
    const int lg = ((lane & 7) ^ lr) << 4;     // pre-swizzled source granule

    for (int pass = 0; pass < 2; ++pass) {
        int wq = blockIdx.x + pass * NBLK;
        if (wq >= 800) break;
        const int x = wq & 7;
        const int q = wq >> 3;
        __syncthreads();   // LDS/norms reuse safety between passes

        if (q < 64) {
            // ---- projection: 64M x 128N ----
            const int sid = x * 64 + q;
            const int m0 = (sid >> 2) * 64;
            const int n0 = (sid & 3) * 128;
            if (t < 64) norms[t] = nrm[m0 + t];
            const char* aB = (const char*)hn + (size_t)(m0 + lr) * 512 + lg;
            const char* bB = (const char*)Wt + (size_t)(n0 + lr) * 512 + lg;
            f32x16 acc[2] = {};

            #define PSTAGE(buf, f2) do {                                          \
                _Pragma("unroll")                                                  \
                for (int k = 0; k < 2; ++k) {                                      \
                    int c = w * 2 + k;                                             \
                    gl_lds16(aB + (size_t)c * 4096 + (f2), (char*)S[buf] + c * 1024); \
                }                                                                  \
                _Pragma("unroll")                                                  \
                for (int k = 0; k < 4; ++k) {                                      \
                    int c = w * 4 + k;                                             \
                    gl_lds16(bB + (size_t)c * 4096 + (f2), (char*)S[buf] + 16384 + c * 1024); \
                }                                                                  \
            } while (0)

            PSTAGE(0, 0);
            __syncthreads();
            #pragma unroll
            for (int st = 0; st < 4; ++st) {
                if (st < 3) PSTAGE((st + 1) & 1, (st + 1) * 128);
                const char* As = (const char*)S[st & 1];
                const char* Bs = As + 16384;
                #pragma unroll
                for (int kc = 0; kc < 4; ++kc) {
                    int kb = kc * 32 + (lane >> 5) * 16;
                    int ra = wr * 32 + (lane & 31);
                    bf16x8 af = *reinterpret_cast<const bf16x8*>(As + ra * 128 + SWZ(ra, kb));
                    #pragma unroll
                    for (int tc = 0; tc < 2; ++tc) {
                        int rb = wc * 64 + tc * 32 + (lane & 31);
                        bf16x8 bf = *reinterpret_cast<const bf16x8*>(Bs + rb * 128 + SWZ(rb, kb));
                        acc[tc] = __builtin_amdgcn_mfma_f32_32x32x16_bf16(af, bf, acc[tc], 0, 0, 0);
                    }
                }
                __syncthreads();
            }
            #undef PSTAGE

            const int head = (n0 >> 6) + wc;
            #pragma unroll
            for (int tc = 0; tc < 2; ++tc) {
                int d = tc * 32 + (lane & 31);
                #pragma unroll
                for (int reg = 0; reg < 16; ++reg) {
                    int ml = wr * 32 + (reg & 3) + 8 * (reg >> 2) + 4 * (lane >> 5);
                    int m = m0 + ml;
                    int b = m >> 10, n = m & 1023;
                    out[((size_t)((b * H + head) * N + n)) * D + d] = acc[tc][reg] * norms[ml];
                }
            }
            const int dl = lane & 31;
            float as0 = a[head * 128 + dl];
            float as1 = a[head * 128 + 32 + dl];
            float at0 = a[head * 128 + 64 + dl];
            float at1 = a[head * 128 + 96 + dl];
            #pragma unroll
            for (int reg = 0; reg < 16; ++reg) {
                float s  = acc[0][reg] * as0 + acc[1][reg] * as1;
                float tg = acc[0][reg] * at0 + acc[1][reg] * at1;
                #pragma unroll
                for (int off = 16; off; off >>= 1) {
                    s  += __shfl_xor(s, off, 64);
                    tg += __shfl_xor(tg, off, 64);
                }
                if (dl == 0) {
                    int ml = wr * 32 + (reg & 3) + 8 * (reg >> 2) + 4 * (lane >> 5);
                    int m = m0 + ml;
                    int b = m >> 10, n = m & 1023;
                    float sc = norms[ml];
                    size_t idx = (size_t)(b * H + head) * N + n;
                    src[idx] = s * sc;
                    tgt[idx] = tg * sc;
                }
            }
        } else {
            // ---- adjacency: upper triangle ----
            const int b = x;
            int pp = q - 64;           // 0..35 -> (ti<=tj)
            int ti = 0;
            while (pp >= 8 - ti) { pp -= 8 - ti; ++ti; }
            const int tj = ti + pp;
            const int i0 = ti * 128, j0 = tj * 128;
            const char* hbB = (const char*)hn + (size_t)b * N * 512;
            const char* aB = hbB + (size_t)(i0 + lr) * 512 + lg;
            const char* bB = hbB + (size_t)(j0 + lr) * 512 + lg;
            f32x16 acc[2][2] = {};

            #define ASTAGE(buf, f2) do {                                          \
                _Pragma("unroll")                                                  \
                for (int k = 0; k < 4; ++k) {                                      \
                    int c = w * 4 + k;                                             \
                    gl_lds16(aB + (size_t)c * 4096 + (f2), (char*)S[buf] + c * 1024); \
                    gl_lds16(bB + (size_t)c * 4096 + (f2), (char*)S[buf] + 16384 + c * 1024); \
                }                                                                  \
            } while (0)

            ASTAGE(0, 0);
            __syncthreads();
            #pragma unroll
            for (int st = 0; st < 4; ++st) {
                if (st < 3) ASTAGE((st + 1) & 1, (st + 1) * 128);
                const char* As = (const char*)S[st & 1];
                const char* Bs = As + 16384;
                #pragma unroll
                for (int kc = 0; kc < 4; ++kc) {
                    int kb = kc * 32 + (lane >> 5) * 16;
                    bf16x8 af[2], bfr[2];
                    #pragma unroll
                    for (int tr = 0; tr < 2; ++tr) {
                        int r = wr * 64 + tr * 32 + (lane & 31);
                        af[tr] = *reinterpret_cast<const bf16x8*>(As + r * 128 + SWZ(r, kb));
                    }
                    #pragma unroll
                    for (int tc = 0; tc < 2; ++tc) {
                        int r = wc * 64 + tc * 32 + (lane & 31);
                        bfr[tc] = *reinterpret_cast<const bf16x8*>(Bs + r * 128 + SWZ(r, kb));
                    }
                    #pragma unroll
                    for (int tr = 0; tr < 2; ++tr)
                        #pragma unroll
                        for (int tc = 0; tc < 2; ++tc)
                            acc[tr][tc] = __builtin_amdgcn_mfma_f32_32x32x16_bf16(af[tr], bfr[tc], acc[tr][tc], 0, 0, 0);
                }
                __syncthreads();
            }
            #undef ASTAGE

            #pragma unroll
            for (int tr = 0; tr < 2; ++tr) {
                #pragma unroll
                for (int tc = 0; tc < 2; ++tc) {
                    int wordcol = (j0 + wc * 64 + tc * 32) >> 5;
                    int rb0 = i0 + wr * 64 + tr * 32;
                    unsigned tw = 0;
                    #pragma unroll
                    for (int reg = 0; reg < 16; ++reg) {
                        bool pr = acc[tr][tc][reg] > 0.5f;
                        unsigned long long msk = __ballot(pr);
                        int rbase = rb0 + (reg & 3) + 8 * (reg >> 2);
                        if (lane == 0)
                            adj[(size_t)(b * N + rbase) * 32 + wordcol] = (unsigned)msk;
                        if (lane == 32)
                            adj[(size_t)(b * N + rbase + 4) * 32 + wordcol] = (unsigned)(msk >> 32);
                        tw |= (pr ? 1u : 0u) << ((reg & 3) + 8 * (reg >> 2) + 4 * (lane >> 5));
                    }
                    if (ti != tj) {
                        tw |= (unsigned)__shfl_xor((int)tw, 32, 64);
                        if (lane < 32) {
                            int cj = j0 + wc * 64 + tc * 32 + lane;
                            adj[(size_t)(b * N + cj) * 32 + (rb0 >> 5)] = tw;
                        }
                    }
                }
            }
        }
    }
    gbar();

    // ---------------- Phase C: fixup attention ----------------
    for (int k = 0; k < 4; ++k) {
        int row = blockIdx.x * 16 + w * 4 + k;   // b*N+i, 0..8191
        const unsigned* arow = adj + (size_t)row * 32;
        unsigned myword = (lane < 32) ? arow[lane] : 0u;
        int cnt = __popc(myword);
        #pragma unroll
        for (int off = 32; off; off >>= 1) cnt += __shfl_xor(cnt, off, 64);
        if (cnt <= 1) continue;  // singleton: out row already correct

        unsigned long long nz = __ballot(myword != 0u);
        int b = row >> 10, i = row & 1023;
        for (int hh = 0; hh < H; ++hh) {
            int bh = b * H + hh;
            const float* outb = out + (size_t)bh * N * D;
            const float* tgtb = tgt + (size_t)bh * N;
            float s_i = src[(size_t)bh * N + i];
            float m = -INFINITY, l = 0.f, acc = 0.f;
            unsigned long long qz = nz;
            while (qz) {
                int wt = __builtin_ctzll(qz);
                qz &= qz - 1;
                unsigned word = (unsigned)__shfl((int)myword, wt, 64);
                while (word) {
                    int jl = __builtin_ctz(word);
                    word &= word - 1;
                    int j = wt * 32 + jl;
                    float e = s_i + tgtb[j];
                    e = e > 0.f ? e : 0.2f * e;
                    float mn = fmaxf(m, e);
                    float scl = __expf(m - mn);  // exp(-inf)=0 on first hit
                    float p   = __expf(e - mn);
                    l = l * scl + p;
                    acc = acc * scl + p * outb[(size_t)j * D + lane];
                    m = mn;
                }
            }
            out[((size_t)bh * N + i) * D + lane] = acc / l;
        }
    }
}

// ---------------------------------------------------------------------------
extern "C" void kernel_launch(void* const* d_in, const int* in_sizes, int n_in,
                              void* d_out, int out_size, void* d_ws, size_t ws_size,
                              hipStream_t stream) {
    const float* h = (const float*)d_in[0];   // [B,N,F]
    const float* W = (const float*)d_in[1];   // [F, H*D]
    const float* a = (const float*)d_in[2];   // [H, 2D, 1]
    float* out = (float*)d_out;               // [B,H,N,D] flat == [B,N,H*D]

    char* ws = (char*)d_ws;
    unsigned* adj = (unsigned*)(ws + 0);          // 1 MB
    float*    src = (float*)(ws + 1048576);       // 256 KB
    float*    tgt = (float*)(ws + 1310720);       // 256 KB
    ushort*   hn  = (ushort*)(ws + 1572864);      // 4 MB
    ushort*   Wt  = (ushort*)(ws + 5767168);      // 256 KB
    float*    nrm = (float*)(ws + 6029312);       // 32 KB

    k_mega<<<dim3(NBLK), 256, 0, stream>>>(h, W, a, hn, Wt, nrm, out, src, tgt, adj);
}

// Round 12
// 36.109 us; speedup vs baseline: 4.7932x; 4.7932x over previous
//
#include <hip/hip_runtime.h>
#include <hip/hip_bf16.h>
#include <math.h>

#define B 8
#define N 1024
#define F 256
#define H 8
#define D 64
#define HD 512  // H*D

typedef __attribute__((ext_vector_type(8))) short bf16x8;
typedef __attribute__((ext_vector_type(16))) float f32x16;

__device__ __forceinline__ ushort f2bf(float x) {
    __hip_bfloat16 b = __float2bfloat16(x);
    return *reinterpret_cast<ushort*>(&b);
}

// async global->LDS, 16B per lane; lds dest = wave-uniform base + lane*16
__device__ __forceinline__ void gl_lds16(const void* g, void* l) {
    __builtin_amdgcn_global_load_lds(
        (__attribute__((address_space(1))) void*)const_cast<void*>(g),
        (__attribute__((address_space(3))) void*)l, 16, 0, 0);
}

#define SWZ(r, byte) ((byte) ^ (((r) & 7) << 4))

// ---------------------------------------------------------------------------
// K1: prep, 512 blocks. Each block: 16 rows (4 waves x 4 rows) of per-row L2
// norm -> hn (normalized bf16) + nrm; plus 256 elements of Wt transpose.
// ---------------------------------------------------------------------------
__global__ __launch_bounds__(256) void k_prep(const float* __restrict__ h,
                                              const float* __restrict__ W,
                                              ushort* __restrict__ hn,
                                              ushort* __restrict__ Wt,
                                              float* __restrict__ nrm) {
    const int t = threadIdx.x;
    const int lane = t & 63;
    const int w = t >> 6;
    #pragma unroll
    for (int k = 0; k < 4; ++k) {
        int row = blockIdx.x * 16 + w * 4 + k;   // 0..8191
        float4 v = *reinterpret_cast<const float4*>(h + (size_t)row * F + lane * 4);
        float s = v.x * v.x + v.y * v.y + v.z * v.z + v.w * v.w;
        #pragma unroll
        for (int off = 32; off; off >>= 1) s += __shfl_xor(s, off, 64);
        float sn = fmaxf(s, 1e-12f);
        float inv = rsqrtf(sn);
        ushort4 on;
        on.x = f2bf(v.x * inv); on.y = f2bf(v.y * inv);
        on.z = f2bf(v.z * inv); on.w = f2bf(v.w * inv);
        *reinterpret_cast<ushort4*>(hn + (size_t)row * F + lane * 4) = on;
        if (lane == 0) nrm[row] = sn * inv;  // = sqrt(sn)
    }
    int idx = blockIdx.x * 256 + t;  // 0..131071, coalesced over n
    Wt[(size_t)(idx & 511) * F + (idx >> 9)] = f2bf(W[idx]);
}

// ---------------------------------------------------------------------------
// K2: fused MFMA kernel, XCD-chunked role mix, 2-phase prefetch dbuf.
// x = bid&7 (XCD/batch), q = bid>>3:
//   q <  64: proj sid = x*64+q -> tile 64(M)x128(N), epilogue writes out+src/tgt
//   q >= 64: adj pair p = q-64 (ti<=tj upper triangle + mirrored words)
// K-loop: prologue stages buf0; step t issues stage(buf[t^1], t+1) BEFORE
// computing buf[t&1]; one barrier per step (stage drain hides under compute).
// ---------------------------------------------------------------------------
__global__ __launch_bounds__(256) void k_gemm(const ushort* __restrict__ hn,
                                              const ushort* __restrict__ Wt,
                                              const float* __restrict__ nrm,
                                              const float* __restrict__ a,
                                              float* __restrict__ out,
                                              float* __restrict__ src,
                                              float* __restrict__ tgt,
                                              unsigned* __restrict__ adj) {
    __shared__ __align__(16) ushort S[2][16384];  // per buf: A 16KB | B 16KB
    __shared__ float norms[64];
    const int x = blockIdx.x & 7;
    const int q = blockIdx.x >> 3;
    const int t = threadIdx.x;
    const int lane = t & 63;
    const int w = t >> 6;
    const int wr = w >> 1, wc = w & 1;
    const int lr = lane >> 3;                  // row within 8-row chunk
    const int lg = ((lane & 7) ^ lr) << 4;     // pre-swizzled source granule

    if (q < 64) {
        // ---------------- projection path: 64M x 128N ----------------
        const int sid = x * 64 + q;
        const int m0 = (sid >> 2) * 64;
        const int n0 = (sid & 3) * 128;
        if (t < 64) norms[t] = nrm[m0 + t];
        const char* aB = (const char*)hn + (size_t)(m0 + lr) * 512 + lg;
        const char* bB = (const char*)Wt + (size_t)(n0 + lr) * 512 + lg;
        f32x16 acc[2] = {};

        #define PSTAGE(buf, f2) do {                                          \
            _Pragma("unroll")                                                  \
            for (int k = 0; k < 2; ++k) {   /* A: 8 chunks / 4 waves */        \
                int c = w * 2 + k;                                             \
                gl_lds16(aB + (size_t)c * 4096 + (f2), (char*)S[buf] + c * 1024); \
            }                                                                  \
            _Pragma("unroll")                                                  \
            for (int k = 0; k < 4; ++k) {   /* B: 16 chunks / 4 waves */       \
                int c = w * 4 + k;                                             \
                gl_lds16(bB + (size_t)c * 4096 + (f2), (char*)S[buf] + 16384 + c * 1024); \
            }                                                                  \
        } while (0)

        PSTAGE(0, 0);
        __syncthreads();
        #pragma unroll
        for (int st = 0; st < 4; ++st) {
            if (st < 3) PSTAGE((st + 1) & 1, (st + 1) * 128);
            const char* As = (const char*)S[st & 1];
            const char* Bs = As + 16384;
            #pragma unroll
            for (int kc = 0; kc < 4; ++kc) {
                int kb = kc * 32 + (lane >> 5) * 16;
                int ra = wr * 32 + (lane & 31);
                bf16x8 af = *reinterpret_cast<const bf16x8*>(As + ra * 128 + SWZ(ra, kb));
                #pragma unroll
                for (int tc = 0; tc < 2; ++tc) {
                    int rb = wc * 64 + tc * 32 + (lane & 31);
                    bf16x8 bf = *reinterpret_cast<const bf16x8*>(Bs + rb * 128 + SWZ(rb, kb));
                    acc[tc] = __builtin_amdgcn_mfma_f32_32x32x16_bf16(af, bf, acc[tc], 0, 0, 0);
                }
            }
            __syncthreads();
        }
        #undef PSTAGE

        // epilogue: scale by row norm, store to out
        const int head = (n0 >> 6) + wc;
        #pragma unroll
        for (int tc = 0; tc < 2; ++tc) {
            int d = tc * 32 + (lane & 31);
            #pragma unroll
            for (int reg = 0; reg < 16; ++reg) {
                int ml = wr * 32 + (reg & 3) + 8 * (reg >> 2) + 4 * (lane >> 5);
                int m = m0 + ml;
                int b = m >> 10, n = m & 1023;
                out[((size_t)((b * H + head) * N + n)) * D + d] = acc[tc][reg] * norms[ml];
            }
        }
        // fused src/tgt (scaled by norm after reduce)
        const int dl = lane & 31;
        float as0 = a[head * 128 + dl];
        float as1 = a[head * 128 + 32 + dl];
        float at0 = a[head * 128 + 64 + dl];
        float at1 = a[head * 128 + 96 + dl];
        #pragma unroll
        for (int reg = 0; reg < 16; ++reg) {
            float s  = acc[0][reg] * as0 + acc[1][reg] * as1;
            float tg = acc[0][reg] * at0 + acc[1][reg] * at1;
            #pragma unroll
            for (int off = 16; off; off >>= 1) {
                s  += __shfl_xor(s, off, 64);
                tg += __shfl_xor(tg, off, 64);
            }
            if (dl == 0) {
                int ml = wr * 32 + (reg & 3) + 8 * (reg >> 2) + 4 * (lane >> 5);
                int m = m0 + ml;
                int b = m >> 10, n = m & 1023;
                float sc = norms[ml];
                size_t idx = (size_t)(b * H + head) * N + n;
                src[idx] = s * sc;
                tgt[idx] = tg * sc;
            }
        }
    } else {
        // ---------------- adjacency path (upper triangle) ----------------
        const int b = x;
        int pp = q - 64;           // 0..35 -> (ti<=tj)
        int ti = 0;
        while (pp >= 8 - ti) { pp -= 8 - ti; ++ti; }
        const int tj = ti + pp;
        const int i0 = ti * 128, j0 = tj * 128;
        const char* hbB = (const char*)hn + (size_t)b * N * 512;
        const char* aB = hbB + (size_t)(i0 + lr) * 512 + lg;
        const char* bB = hbB + (size_t)(j0 + lr) * 512 + lg;
        f32x16 acc[2][2] = {};

        #define ASTAGE(buf, f2) do {                                          \
            _Pragma("unroll")                                                  \
            for (int k = 0; k < 4; ++k) {   /* 16+16 chunks / 4 waves */       \
                int c = w * 4 + k;                                             \
                gl_lds16(aB + (size_t)c * 4096 + (f2), (char*)S[buf] + c * 1024); \
                gl_lds16(bB + (size_t)c * 4096 + (f2), (char*)S[buf] + 16384 + c * 1024); \
            }                                                                  \
        } while (0)

        ASTAGE(0, 0);
        __syncthreads();
        #pragma unroll
        for (int st = 0; st < 4; ++st) {
            if (st < 3) ASTAGE((st + 1) & 1, (st + 1) * 128);
            const char* As = (const char*)S[st & 1];
            const char* Bs = As + 16384;
            #pragma unroll
            for (int kc = 0; kc < 4; ++kc) {
                int kb = kc * 32 + (lane >> 5) * 16;
                bf16x8 af[2], bfr[2];
                #pragma unroll
                for (int tr = 0; tr < 2; ++tr) {
                    int r = wr * 64 + tr * 32 + (lane & 31);
                    af[tr] = *reinterpret_cast<const bf16x8*>(As + r * 128 + SWZ(r, kb));
                }
                #pragma unroll
                for (int tc = 0; tc < 2; ++tc) {
                    int r = wc * 64 + tc * 32 + (lane & 31);
                    bfr[tc] = *reinterpret_cast<const bf16x8*>(Bs + r * 128 + SWZ(r, kb));
                }
                #pragma unroll
                for (int tr = 0; tr < 2; ++tr)
                    #pragma unroll
                    for (int tc = 0; tc < 2; ++tc)
                        acc[tr][tc] = __builtin_amdgcn_mfma_f32_32x32x16_bf16(af[tr], bfr[tc], acc[tr][tc], 0, 0, 0);
            }
            __syncthreads();
        }
        #undef ASTAGE

        #pragma unroll
        for (int tr = 0; tr < 2; ++tr) {
            #pragma unroll
            for (int tc = 0; tc < 2; ++tc) {
                int wordcol = (j0 + wc * 64 + tc * 32) >> 5;
                int rb0 = i0 + wr * 64 + tr * 32;
                unsigned tw = 0;
                #pragma unroll
                for (int reg = 0; reg < 16; ++reg) {
                    bool pr = acc[tr][tc][reg] > 0.5f;
                    unsigned long long msk = __ballot(pr);
                    int rbase = rb0 + (reg & 3) + 8 * (reg >> 2);
                    if (lane == 0)
                        adj[(size_t)(b * N + rbase) * 32 + wordcol] = (unsigned)msk;
                    if (lane == 32)
                        adj[(size_t)(b * N + rbase + 4) * 32 + wordcol] = (unsigned)(msk >> 32);
                    tw |= (pr ? 1u : 0u) << ((reg & 3) + 8 * (reg >> 2) + 4 * (lane >> 5));
                }
                if (ti != tj) {
                    // mirrored write: word for column cj over this 32-row group
                    tw |= (unsigned)__shfl_xor((int)tw, 32, 64);
                    if (lane < 32) {
                        int cj = j0 + wc * 64 + tc * 32 + lane;
                        adj[(size_t)(b * N + cj) * 32 + (rb0 >> 5)] = tw;
                    }
                }
            }
        }
    }
}

// ---------------------------------------------------------------------------
// K3: fixup-only attention. 4 rows per wave; singleton rows (all rows, for
// this data distribution) skip — out already holds the projected row.
// Multi-neighbor rows do full online-softmax reading neighbor rows from out.
// ---------------------------------------------------------------------------
__global__ void k_attn(const float* __restrict__ src, const float* __restrict__ tgt,
                       const unsigned* __restrict__ adj, float* __restrict__ out) {
    int wave = (blockIdx.x * 256 + threadIdx.x) >> 6;  // 0..2047
    int lane = threadIdx.x & 63;
    for (int k = 0; k < 4; ++k) {
        int row = wave * 4 + k;      // b*N+i, 0..8191
        const unsigned* arow = adj + (size_t)row * 32;
        unsigned myword = (lane < 32) ? arow[lane] : 0u;
        int cnt = __popc(myword);
        #pragma unroll
        for (int off = 32; off; off >>= 1) cnt += __shfl_xor(cnt, off, 64);
        if (cnt <= 1) continue;  // singleton: out row already correct

        unsigned long long nz = __ballot(myword != 0u);
        int b = row >> 10, i = row & 1023;
        for (int hh = 0; hh < H; ++hh) {
            int bh = b * H + hh;
            const float* outb = out + (size_t)bh * N * D;
            const float* tgtb = tgt + (size_t)bh * N;
            float s_i = src[(size_t)bh * N + i];
            float m = -INFINITY, l = 0.f, acc = 0.f;
            unsigned long long qz = nz;
            while (qz) {
                int wt = __builtin_ctzll(qz);
                qz &= qz - 1;
                unsigned word = (unsigned)__shfl((int)myword, wt, 64);
                while (word) {
                    int jl = __builtin_ctz(word);
                    word &= word - 1;
                    int j = wt * 32 + jl;
                    float e = s_i + tgtb[j];
                    e = e > 0.f ? e : 0.2f * e;
                    float mn = fmaxf(m, e);
                    float scl = __expf(m - mn);  // exp(-inf)=0 on first hit
                    float p   = __expf(e - mn);
                    l = l * scl + p;
                    acc = acc * scl + p * outb[(size_t)j * D + lane];
                    m = mn;
                }
            }
            out[((size_t)bh * N + i) * D + lane] = acc / l;
        }
    }
}

// ---------------------------------------------------------------------------
extern "C" void kernel_launch(void* const* d_in, const int* in_sizes, int n_in,
                              void* d_out, int out_size, void* d_ws, size_t ws_size,
                              hipStream_t stream) {
    const float* h = (const float*)d_in[0];   // [B,N,F]
    const float* W = (const float*)d_in[1];   // [F, H*D]
    const float* a = (const float*)d_in[2];   // [H, 2D, 1]
    float* out = (float*)d_out;               // [B,H,N,D] flat == [B,N,H*D]

    char* ws = (char*)d_ws;
    unsigned* adj = (unsigned*)(ws + 0);          // 1 MB
    float*    src = (float*)(ws + 1048576);       // 256 KB
    float*    tgt = (float*)(ws + 1310720);       // 256 KB
    ushort*   hn  = (ushort*)(ws + 1572864);      // 4 MB
    ushort*   Wt  = (ushort*)(ws + 5767168);      // 256 KB
    float*    nrm = (float*)(ws + 6029312);       // 32 KB

    k_prep<<<dim3(512), 256, 0, stream>>>(h, W, hn, Wt, nrm);
    k_gemm<<<dim3(800), 256, 0, stream>>>(hn, Wt, nrm, a, out, src, tgt, adj);
    k_attn<<<dim3(512), 256, 0, stream>>>(src, tgt, adj, out);
}

// Round 13
// 33.344 us; speedup vs baseline: 5.1907x; 1.0829x over previous
//
#include <hip/hip_runtime.h>
#include <hip/hip_bf16.h>
#include <math.h>

#define B 8
#define N 1024
#define F 256
#define H 8
#define D 64
#define HD 512  // H*D

typedef __attribute__((ext_vector_type(8))) short bf16x8;
typedef __attribute__((ext_vector_type(16))) float f32x16;

__device__ __forceinline__ ushort f2bf(float x) {
    __hip_bfloat16 b = __float2bfloat16(x);
    return *reinterpret_cast<ushort*>(&b);
}

// async global->LDS, 16B per lane; lds dest = wave-uniform base + lane*16
__device__ __forceinline__ void gl_lds16(const void* g, void* l) {
    __builtin_amdgcn_global_load_lds(
        (__attribute__((address_space(1))) void*)const_cast<void*>(g),
        (__attribute__((address_space(3))) void*)l, 16, 0, 0);
}

#define SWZ(r, byte) ((byte) ^ (((r) & 7) << 4))

// ---------------------------------------------------------------------------
// K1: prep. blocks 0..2047: per-row L2 norm -> hn (normalized bf16) + nrm
// (= sqrt(max(ss,eps))). blocks 2048..2559: Wt[n][k] = bf16(W[k][n]).
// ---------------------------------------------------------------------------
__global__ __launch_bounds__(256) void k_prep(const float* __restrict__ h,
                                              const float* __restrict__ W,
                                              ushort* __restrict__ hn,
                                              ushort* __restrict__ Wt,
                                              float* __restrict__ nrm) {
    if (blockIdx.x < 2048) {
        int row = (blockIdx.x * 256 + threadIdx.x) >> 6;
        int lane = threadIdx.x & 63;
        float4 v = *reinterpret_cast<const float4*>(h + (size_t)row * F + lane * 4);
        float s = v.x * v.x + v.y * v.y + v.z * v.z + v.w * v.w;
        #pragma unroll
        for (int off = 32; off; off >>= 1) s += __shfl_xor(s, off, 64);
        float sn = fmaxf(s, 1e-12f);
        float inv = rsqrtf(sn);
        ushort4 on;
        on.x = f2bf(v.x * inv); on.y = f2bf(v.y * inv);
        on.z = f2bf(v.z * inv); on.w = f2bf(v.w * inv);
        *reinterpret_cast<ushort4*>(hn + (size_t)row * F + lane * 4) = on;
        if (lane == 0) nrm[row] = sn * inv;  // = sqrt(sn)
    } else {
        int idx = (blockIdx.x - 2048) * 256 + threadIdx.x;  // coalesced over n
        int k = idx >> 9;
        int n = idx & 511;
        Wt[(size_t)n * F + k] = f2bf(W[idx]);
    }
}

// ---------------------------------------------------------------------------
// K2: fused MFMA kernel, heavy-first dispatch order, 2-phase prefetch dbuf.
//   bid <  288: adj pair p = bid>>3 (0..35), batch x = bid&7; tiles ti<=tj
//               (128x128 upper triangle + mirrored transposed words)
//   bid >= 288: proj p = bid-288, x = p&7, sid = x*64 + (p>>3)... tile
//               64(M)x128(N), epilogue writes out + src/tgt
// Heavy adj blocks dispatch first so the 800-block grid's tail (last
// scheduling round at 2 blocks/CU) is light proj blocks.
// K-loop: prologue stages buf0; step st issues stage(buf^1, st+1) BEFORE
// computing buf; one barrier per step (stage drain hides under compute).
// ---------------------------------------------------------------------------
__global__ __launch_bounds__(256) void k_gemm(const ushort* __restrict__ hn,
                                              const ushort* __restrict__ Wt,
                                              const float* __restrict__ nrm,
                                              const float* __restrict__ a,
                                              float* __restrict__ out,
                                              float* __restrict__ src,
                                              float* __restrict__ tgt,
                                              unsigned* __restrict__ adj) {
    __shared__ __align__(16) ushort S[2][16384];  // per buf: A 16KB | B 16KB
    __shared__ float norms[64];
    const int t = threadIdx.x;
    const int lane = t & 63;
    const int w = t >> 6;
    const int wr = w >> 1, wc = w & 1;
    const int lr = lane >> 3;                  // row within 8-row chunk
    const int lg = ((lane & 7) ^ lr) << 4;     // pre-swizzled source granule

    if (blockIdx.x >= 288) {
        // ---------------- projection path: 64M x 128N ----------------
        const int p = blockIdx.x - 288;
        const int x = p & 7;
        const int sid = x * 64 + (p >> 3);
        const int m0 = (sid >> 2) * 64;
        const int n0 = (sid & 3) * 128;
        if (t < 64) norms[t] = nrm[m0 + t];
        const char* aB = (const char*)hn + (size_t)(m0 + lr) * 512 + lg;
        const char* bB = (const char*)Wt + (size_t)(n0 + lr) * 512 + lg;
        f32x16 acc[2] = {};

        #define PSTAGE(buf, f2) do {                                          \
            _Pragma("unroll")                                                  \
            for (int k = 0; k < 2; ++k) {   /* A: 8 chunks / 4 waves */        \
                int c = w * 2 + k;                                             \
                gl_lds16(aB + (size_t)c * 4096 + (f2), (char*)S[buf] + c * 1024); \
            }                                                                  \
            _Pragma("unroll")                                                  \
            for (int k = 0; k < 4; ++k) {   /* B: 16 chunks / 4 waves */       \
                int c = w * 4 + k;                                             \
                gl_lds16(bB + (size_t)c * 4096 + (f2), (char*)S[buf] + 16384 + c * 1024); \
            }                                                                  \
        } while (0)

        PSTAGE(0, 0);
        __syncthreads();
        #pragma unroll
        for (int st = 0; st < 4; ++st) {
            if (st < 3) PSTAGE((st + 1) & 1, (st + 1) * 128);
            const char* As = (const char*)S[st & 1];
            const char* Bs = As + 16384;
            #pragma unroll
            for (int kc = 0; kc < 4; ++kc) {
                int kb = kc * 32 + (lane >> 5) * 16;
                int ra = wr * 32 + (lane & 31);
                bf16x8 af = *reinterpret_cast<const bf16x8*>(As + ra * 128 + SWZ(ra, kb));
                #pragma unroll
                for (int tc = 0; tc < 2; ++tc) {
                    int rb = wc * 64 + tc * 32 + (lane & 31);
                    bf16x8 bf = *reinterpret_cast<const bf16x8*>(Bs + rb * 128 + SWZ(rb, kb));
                    acc[tc] = __builtin_amdgcn_mfma_f32_32x32x16_bf16(af, bf, acc[tc], 0, 0, 0);
                }
            }
            __syncthreads();
        }
        #undef PSTAGE

        // epilogue: scale by row norm, store to out
        const int head = (n0 >> 6) + wc;
        #pragma unroll
        for (int tc = 0; tc < 2; ++tc) {
            int d = tc * 32 + (lane & 31);
            #pragma unroll
            for (int reg = 0; reg < 16; ++reg) {
                int ml = wr * 32 + (reg & 3) + 8 * (reg >> 2) + 4 * (lane >> 5);
                int m = m0 + ml;
                int b = m >> 10, n = m & 1023;
                out[((size_t)((b * H + head) * N + n)) * D + d] = acc[tc][reg] * norms[ml];
            }
        }
        // fused src/tgt (scaled by norm after reduce)
        const int dl = lane & 31;
        float as0 = a[head * 128 + dl];
        float as1 = a[head * 128 + 32 + dl];
        float at0 = a[head * 128 + 64 + dl];
        float at1 = a[head * 128 + 96 + dl];
        #pragma unroll
        for (int reg = 0; reg < 16; ++reg) {
            float s  = acc[0][reg] * as0 + acc[1][reg] * as1;
            float tg = acc[0][reg] * at0 + acc[1][reg] * at1;
            #pragma unroll
            for (int off = 16; off; off >>= 1) {
                s  += __shfl_xor(s, off, 64);
                tg += __shfl_xor(tg, off, 64);
            }
            if (dl == 0) {
                int ml = wr * 32 + (reg & 3) + 8 * (reg >> 2) + 4 * (lane >> 5);
                int m = m0 + ml;
                int b = m >> 10, n = m & 1023;
                float sc = norms[ml];
                size_t idx = (size_t)(b * H + head) * N + n;
                src[idx] = s * sc;
                tgt[idx] = tg * sc;
            }
        }
    } else {
        // ---------------- adjacency path (upper triangle) ----------------
        const int x = blockIdx.x & 7;
        const int b = x;
        int pp = blockIdx.x >> 3;  // 0..35 -> (ti<=tj)
        int ti = 0;
        while (pp >= 8 - ti) { pp -= 8 - ti; ++ti; }
        const int tj = ti + pp;
        const int i0 = ti * 128, j0 = tj * 128;
        const char* hbB = (const char*)hn + (size_t)b * N * 512;
        const char* aB = hbB + (size_t)(i0 + lr) * 512 + lg;
        const char* bB = hbB + (size_t)(j0 + lr) * 512 + lg;
        f32x16 acc[2][2] = {};

        #define ASTAGE(buf, f2) do {                                          \
            _Pragma("unroll")                                                  \
            for (int k = 0; k < 4; ++k) {   /* 16+16 chunks / 4 waves */       \
                int c = w * 4 + k;                                             \
                gl_lds16(aB + (size_t)c * 4096 + (f2), (char*)S[buf] + c * 1024); \
                gl_lds16(bB + (size_t)c * 4096 + (f2), (char*)S[buf] + 16384 + c * 1024); \
            }                                                                  \
        } while (0)

        ASTAGE(0, 0);
        __syncthreads();
        #pragma unroll
        for (int st = 0; st < 4; ++st) {
            if (st < 3) ASTAGE((st + 1) & 1, (st + 1) * 128);
            const char* As = (const char*)S[st & 1];
            const char* Bs = As + 16384;
            #pragma unroll
            for (int kc = 0; kc < 4; ++kc) {
                int kb = kc * 32 + (lane >> 5) * 16;
                bf16x8 af[2], bfr[2];
                #pragma unroll
                for (int tr = 0; tr < 2; ++tr) {
                    int r = wr * 64 + tr * 32 + (lane & 31);
                    af[tr] = *reinterpret_cast<const bf16x8*>(As + r * 128 + SWZ(r, kb));
                }
                #pragma unroll
                for (int tc = 0; tc < 2; ++tc) {
                    int r = wc * 64 + tc * 32 + (lane & 31);
                    bfr[tc] = *reinterpret_cast<const bf16x8*>(Bs + r * 128 + SWZ(r, kb));
                }
                #pragma unroll
                for (int tr = 0; tr < 2; ++tr)
                    #pragma unroll
                    for (int tc = 0; tc < 2; ++tc)
                        acc[tr][tc] = __builtin_amdgcn_mfma_f32_32x32x16_bf16(af[tr], bfr[tc], acc[tr][tc], 0, 0, 0);
            }
            __syncthreads();
        }
        #undef ASTAGE

        #pragma unroll
        for (int tr = 0; tr < 2; ++tr) {
            #pragma unroll
            for (int tc = 0; tc < 2; ++tc) {
                int wordcol = (j0 + wc * 64 + tc * 32) >> 5;
                int rb0 = i0 + wr * 64 + tr * 32;
                unsigned tw = 0;
                #pragma unroll
                for (int reg = 0; reg < 16; ++reg) {
                    bool pr = acc[tr][tc][reg] > 0.5f;
                    unsigned long long msk = __ballot(pr);
                    int rbase = rb0 + (reg & 3) + 8 * (reg >> 2);
                    if (lane == 0)
                        adj[(size_t)(b * N + rbase) * 32 + wordcol] = (unsigned)msk;
                    if (lane == 32)
                        adj[(size_t)(b * N + rbase + 4) * 32 + wordcol] = (unsigned)(msk >> 32);
                    tw |= (pr ? 1u : 0u) << ((reg & 3) + 8 * (reg >> 2) + 4 * (lane >> 5));
                }
                if (ti != tj) {
                    // mirrored write: word for column cj over this 32-row group
                    tw |= (unsigned)__shfl_xor((int)tw, 32, 64);
                    if (lane < 32) {
                        int cj = j0 + wc * 64 + tc * 32 + lane;
                        adj[(size_t)(b * N + cj) * 32 + (rb0 >> 5)] = tw;
                    }
                }
            }
        }
    }
}

// ---------------------------------------------------------------------------
// K3: fixup-only attention. 4 rows per wave; singleton rows (all rows, for
// this data distribution) skip — out already holds the projected row.
// Multi-neighbor rows do full online-softmax reading neighbor rows from out.
// ---------------------------------------------------------------------------
__global__ void k_attn(const float* __restrict__ src, const float* __restrict__ tgt,
                       const unsigned* __restrict__ adj, float* __restrict__ out) {
    int wave = (blockIdx.x * 256 + threadIdx.x) >> 6;  // 0..2047
    int lane = threadIdx.x & 63;
    for (int k = 0; k < 4; ++k) {
        int row = wave * 4 + k;      // b*N+i, 0..8191
        const unsigned* arow = adj + (size_t)row * 32;
        unsigned myword = (lane < 32) ? arow[lane] : 0u;
        int cnt = __popc(myword);
        #pragma unroll
        for (int off = 32; off; off >>= 1) cnt += __shfl_xor(cnt, off, 64);
        if (cnt <= 1) continue;  // singleton: out row already correct

        unsigned long long nz = __ballot(myword != 0u);
        int b = row >> 10, i = row & 1023;
        for (int hh = 0; hh < H; ++hh) {
            int bh = b * H + hh;
            const float* outb = out + (size_t)bh * N * D;
            const float* tgtb = tgt + (size_t)bh * N;
            float s_i = src[(size_t)bh * N + i];
            float m = -INFINITY, l = 0.f, acc = 0.f;
            unsigned long long qz = nz;
            while (qz) {
                int wt = __builtin_ctzll(qz);
                qz &= qz - 1;
                unsigned word = (unsigned)__shfl((int)myword, wt, 64);
                while (word) {
                    int jl = __builtin_ctz(word);
                    word &= word - 1;
                    int j = wt * 32 + jl;
                    float e = s_i + tgtb[j];
                    e = e > 0.f ? e : 0.2f * e;
                    float mn = fmaxf(m, e);
                    float scl = __expf(m - mn);  // exp(-inf)=0 on first hit
                    float p   = __expf(e - mn);
                    l = l * scl + p;
                    acc = acc * scl + p * outb[(size_t)j * D + lane];
                    m = mn;
                }
            }
            out[((size_t)bh * N + i) * D + lane] = acc / l;
        }
    }
}

// ---------------------------------------------------------------------------
extern "C" void kernel_launch(void* const* d_in, const int* in_sizes, int n_in,
                              void* d_out, int out_size, void* d_ws, size_t ws_size,
                              hipStream_t stream) {
    const float* h = (const float*)d_in[0];   // [B,N,F]
    const float* W = (const float*)d_in[1];   // [F, H*D]
    const float* a = (const float*)d_in[2];   // [H, 2D, 1]
    float* out = (float*)d_out;               // [B,H,N,D] flat == [B,N,H*D]

    char* ws = (char*)d_ws;
    unsigned* adj = (unsigned*)(ws + 0);          // 1 MB
    float*    src = (float*)(ws + 1048576);       // 256 KB
    float*    tgt = (float*)(ws + 1310720);       // 256 KB
    ushort*   hn  = (ushort*)(ws + 1572864);      // 4 MB
    ushort*   Wt  = (ushort*)(ws + 5767168);      // 256 KB
    float*    nrm = (float*)(ws + 6029312);       // 32 KB

    k_prep<<<dim3(2560), 256, 0, stream>>>(h, W, hn, Wt, nrm);
    k_gemm<<<dim3(800), 256, 0, stream>>>(hn, Wt, nrm, a, out, src, tgt, adj);
    k_attn<<<dim3(512), 256, 0, stream>>>(src, tgt, adj, out);
}